// Round 14
// baseline (319.493 us; speedup 1.0000x reference)
//
#include <hip/hip_runtime.h>
#include <hip/hip_bf16.h>
#include <hip/hip_cooperative_groups.h>

namespace cg = cooperative_groups;

#define D 256

typedef __attribute__((ext_vector_type(8))) short bf16x8;
typedef __attribute__((ext_vector_type(4))) short s16x4;
typedef __attribute__((ext_vector_type(4))) float f32x4;

#define MFMA __builtin_amdgcn_mfma_f32_16x16x32_bf16

__device__ __forceinline__ float s2f(short u) {
    union { unsigned int i; float f; } c;
    c.i = ((unsigned int)(unsigned short)u) << 16;
    return c.f;
}
__device__ __forceinline__ short f2s(float f) {
    union { float f; unsigned int u; } c; c.f = f;
    unsigned int u = c.u;
    u += 0x7fffu + ((u >> 16) & 1u);
    return (short)(u >> 16);
}

// ---------------- fused front-end (cooperative): prep -> count -> scan -> fill ----------------
__global__ __launch_bounds__(256) void front_kernel(
    const float* __restrict__ atom, short* __restrict__ atom_bf,
    const float* __restrict__ W_align, const float* __restrict__ b_align,
    const float* __restrict__ g, const float* __restrict__ bb,
    const float* __restrict__ mn, const float* __restrict__ vr,
    float* __restrict__ p0p, float* __restrict__ p1p,
    const float* __restrict__ Wa, short* __restrict__ Wa_bf,
    const float* __restrict__ Wi, short* __restrict__ Wi_bf,
    const float* __restrict__ Wh, short* __restrict__ Wh_bf,
    int* __restrict__ cnt, int* __restrict__ cursor,
    int* __restrict__ offv, int* __restrict__ dlist,
    const int* __restrict__ src, const int* __restrict__ dst,
    int N, int E, int NROWB, int WCVTB, int TOTB)
{
    __shared__ int sums[256];
    cg::grid_group grid = cg::this_grid();
    int tid = threadIdx.x;

    // ---- phase A: atom cvt + p0p1, weight cvt, CSR zero ----
    for (int vb = blockIdx.x; vb < TOTB; vb += gridDim.x) {
        int b = vb;
        if (b < NROWB) {
            int wave = tid >> 6, lane = tid & 63;
            int row = b * 4 + wave;
            if (row < N) {
                float4 a = *(const float4*)(atom + (size_t)row * D + lane * 4);
                s16x4 o; o[0] = f2s(a.x); o[1] = f2s(a.y); o[2] = f2s(a.z); o[3] = f2s(a.w);
                ((s16x4*)(atom_bf + (size_t)row * D))[lane] = o;
                float4 w0 = *(const float4*)(W_align + lane * 4);
                float4 w1 = *(const float4*)(W_align + D + lane * 4);
                float d0 = a.x * w0.x + a.y * w0.y + a.z * w0.z + a.w * w0.w;
                float d1 = a.x * w1.x + a.y * w1.y + a.z * w1.z + a.w * w1.w;
                #pragma unroll
                for (int s = 32; s > 0; s >>= 1) {
                    d0 += __shfl_xor(d0, s, 64);
                    d1 += __shfl_xor(d1, s, 64);
                }
                if (lane == 0) {
                    float A = rsqrtf(vr[0] + 1e-6f) * g[0];
                    p0p[row] = A * (d0 + b_align[0]) + bb[0] - A * mn[0];
                    p1p[row] = A * d1;
                }
            }
        } else {
            b -= NROWB;
            if (b < WCVTB) {
                int nW4 = D * D / 4, nG4 = 3 * D * D / 4;
                int j = b * 256 + tid;
                const float* sp = 0; short* dp = 0;
                if (j < nW4) { sp = Wa; dp = Wa_bf; }
                else { j -= nW4;
                    if (j < nG4) { sp = Wi; dp = Wi_bf; }
                    else { j -= nG4;
                        if (j < nG4) { sp = Wh; dp = Wh_bf; }
                    }
                }
                if (sp) {
                    float4 v = ((const float4*)sp)[j];
                    s16x4 o; o[0] = f2s(v.x); o[1] = f2s(v.y); o[2] = f2s(v.z); o[3] = f2s(v.w);
                    ((s16x4*)dp)[j] = o;
                }
            } else {
                b -= WCVTB;
                int i = b * 256 + tid;
                if (i < N) { cnt[i] = 0; cursor[i] = 0; }
            }
        }
    }
    grid.sync();

    // ---- phase B: histogram of src ----
    for (int e = blockIdx.x * 256 + tid; e < E; e += gridDim.x * 256)
        atomicAdd(&cnt[src[e]], 1);
    grid.sync();

    // ---- phase C: exclusive scan (block 0 only) ----
    if (blockIdx.x == 0) {
        int CH = (N + 255) / 256;
        int beg = tid * CH;
        int end = beg + CH; if (end > N) end = N;
        if (beg > N) beg = N;
        int s = 0;
        for (int i = beg; i < end; i++) s += cnt[i];
        sums[tid] = s;
        __syncthreads();
        for (int d = 1; d < 256; d <<= 1) {
            int x = (tid >= d) ? sums[tid - d] : 0;
            __syncthreads();
            sums[tid] += x;
            __syncthreads();
        }
        int run = (tid > 0) ? sums[tid - 1] : 0;
        for (int i = beg; i < end; i++) { offv[i] = run; run += cnt[i]; }
        if (end == N) offv[N] = run;
    }
    grid.sync();

    // ---- phase D: fill dst-valued edge lists ----
    for (int e = blockIdx.x * 256 + tid; e < E; e += gridDim.x * 256) {
        int s = src[e];
        int p = atomicAdd(&cursor[s], 1);
        dlist[offv[s] + p] = dst[e];
    }
}

// ---------------- hA = BN(atom @ W_att^T + b_att), MFMA + lane-ordered LDS B ----------------
__global__ __launch_bounds__(256) void hA_kernel(
    const short* __restrict__ atom_bf, const short* __restrict__ W_bf,
    const float* __restrict__ bias,
    const float* __restrict__ g, const float* __restrict__ bb,
    const float* __restrict__ mn, const float* __restrict__ vr,
    short* __restrict__ hA, int N, int NB)
{
    __shared__ short Bs[2048 * 8];       // 32KB, lane-ordered chunks
    int bi = blockIdx.x;
    int xcd = bi & 7, rest = bi >> 3;
    int cb = rest & 3, gh = rest >> 2;
    int gg = gh * 8 + xcd;
    if (gg >= NB) return;
    int c0 = cb * 64;
    int tid = threadIdx.x;
    for (int c = tid; c < 2048; c += 256) {
        int l15c = c & 15, quadc = (c >> 4) & 3, t2 = c >> 6;
        int kkc = t2 & 7, jc = t2 >> 3;
        bf16x8 v = *(const bf16x8*)(W_bf + (size_t)(c0 + jc * 16 + l15c) * D + quadc * 8 + kkc * 32);
        *(bf16x8*)(&Bs[c * 8]) = v;
    }
    __syncthreads();

    int wave = tid >> 6, lane = tid & 63;
    int quad = lane >> 4, l15 = lane & 15;
    int m0 = gg * 128 + wave * 16;
    int ar0 = m0 + l15;       if (ar0 > N - 1) ar0 = N - 1;
    int ar1 = m0 + 64 + l15;  if (ar1 > N - 1) ar1 = N - 1;
    const short* ap0 = atom_bf + (size_t)ar0 * D + quad * 8;
    const short* ap1 = atom_bf + (size_t)ar1 * D + quad * 8;
    const short* lb = &Bs[lane * 8];
    f32x4 acc[2][4];
    #pragma unroll
    for (int t = 0; t < 2; t++)
        #pragma unroll
        for (int j = 0; j < 4; j++) acc[t][j] = (f32x4){0,0,0,0};
    #pragma unroll
    for (int kk = 0; kk < 8; kk++) {
        int k = kk * 32;
        bf16x8 a0 = *(const bf16x8*)(ap0 + k);
        bf16x8 a1 = *(const bf16x8*)(ap1 + k);
        bf16x8 b0 = *(const bf16x8*)(lb + (0 * 8 + kk) * 512);
        bf16x8 b1 = *(const bf16x8*)(lb + (1 * 8 + kk) * 512);
        bf16x8 b2 = *(const bf16x8*)(lb + (2 * 8 + kk) * 512);
        bf16x8 b3 = *(const bf16x8*)(lb + (3 * 8 + kk) * 512);
        acc[0][0] = MFMA(a0, b0, acc[0][0], 0, 0, 0);
        acc[0][1] = MFMA(a0, b1, acc[0][1], 0, 0, 0);
        acc[0][2] = MFMA(a0, b2, acc[0][2], 0, 0, 0);
        acc[0][3] = MFMA(a0, b3, acc[0][3], 0, 0, 0);
        acc[1][0] = MFMA(a1, b0, acc[1][0], 0, 0, 0);
        acc[1][1] = MFMA(a1, b1, acc[1][1], 0, 0, 0);
        acc[1][2] = MFMA(a1, b2, acc[1][2], 0, 0, 0);
        acc[1][3] = MFMA(a1, b3, acc[1][3], 0, 0, 0);
    }
    #pragma unroll
    for (int j = 0; j < 4; j++) {
        int col = c0 + j * 16 + l15;
        float sc = rsqrtf(vr[col] + 1e-6f) * g[col];
        float sh = bb[col] - mn[col] * sc;
        float bi_ = bias[col];
        #pragma unroll
        for (int t = 0; t < 2; t++) {
            #pragma unroll
            for (int r = 0; r < 4; r++) {
                int row = m0 + t * 64 + quad * 4 + r;
                if (row < N) hA[(size_t)row * D + col] = f2s((acc[t][j][r] + bi_) * sc + sh);
            }
        }
    }
}

// ---------------- fused score+softmax+aggregate (wave per atom), bf16 ctx out ----------------
__global__ __launch_bounds__(256) void agg_kernel(
    const int* __restrict__ off, const int* __restrict__ dlist,
    const float* __restrict__ p0p, const float* __restrict__ p1p,
    const short* __restrict__ hA, short* __restrict__ ctx, int N)
{
    int w = (blockIdx.x * blockDim.x + threadIdx.x) >> 6;
    int lane = threadIdx.x & 63;
    if (w >= N) return;
    int beg = off[w], end = off[w + 1];
    float u = p0p[w];
    float m = -INFINITY;
    for (int j = beg + lane; j < end; j += 64) {
        float x = u + p1p[dlist[j]];
        x = x > 0.f ? x : 0.01f * x;
        m = fmaxf(m, x);
    }
    #pragma unroll
    for (int o = 32; o > 0; o >>= 1) m = fmaxf(m, __shfl_xor(m, o, 64));
    float sum = 0.f;
    for (int j = beg + lane; j < end; j += 64) {
        float x = u + p1p[dlist[j]];
        x = x > 0.f ? x : 0.01f * x;
        sum += __expf(x - m);
    }
    #pragma unroll
    for (int o = 32; o > 0; o >>= 1) sum += __shfl_xor(sum, o, 64);
    float inv = 1.f / (sum + 1e-8f);
    int half = lane >> 5, l32 = lane & 31;
    float acc[8] = {0.f,0.f,0.f,0.f,0.f,0.f,0.f,0.f};
    for (int j = beg + half; j < end; j += 2) {
        int d = dlist[j];
        float x = u + p1p[d];
        x = x > 0.f ? x : 0.01f * x;
        float coef = __expf(x - m) * inv;
        bf16x8 h = *(const bf16x8*)(hA + (size_t)d * D + l32 * 8);
        #pragma unroll
        for (int i = 0; i < 8; i++) acc[i] += coef * s2f(h[i]);
    }
    #pragma unroll
    for (int i = 0; i < 8; i++) acc[i] += __shfl_xor(acc[i], 32, 64);
    if (half == 0) {
        bf16x8 o;
        #pragma unroll
        for (int i = 0; i < 8; i++) {
            float v = acc[i];
            v = v > 0.f ? v : __expf(v) - 1.f;
            o[i] = f2s(v);
        }
        *(bf16x8*)(ctx + (size_t)w * D + l32 * 8) = o;
    }
}

// ---------------- fused GRU cell, MFMA + lane-ordered LDS B; OUTPUT FLOAT32 ----------------
__global__ __launch_bounds__(256) void gru_kernel(
    const short* __restrict__ ctx, const short* __restrict__ atom_bf,
    const short* __restrict__ W_ih, const short* __restrict__ W_hh,
    const float* __restrict__ b_ih, const float* __restrict__ b_hh,
    float* __restrict__ out, int N, int NB)
{
    __shared__ short Bs[3072 * 8];   // 48KB, lane-ordered chunks
    int bi = blockIdx.x;
    int xcd = bi & 7, rest = bi >> 3;
    int cb = rest & 15, gh = rest >> 4;
    int gg = gh * 8 + xcd;
    if (gg >= NB) return;
    int c0 = cb * 16;
    int tid = threadIdx.x;
    for (int c = tid; c < 3072; c += 256) {
        int l15c = c & 15, quadc = (c >> 4) & 3, t2 = c >> 6;
        int kkc = t2 & 7, gate = t2 >> 3;
        const short* srcp = (gate < 3)
            ? W_ih + (size_t)(gate * 256 + c0 + l15c) * D + quadc * 8 + kkc * 32
            : W_hh + (size_t)((gate - 3) * 256 + c0 + l15c) * D + quadc * 8 + kkc * 32;
        *(bf16x8*)(&Bs[c * 8]) = *(const bf16x8*)srcp;
    }
    __syncthreads();

    int wave = tid >> 6, lane = tid & 63;
    int quad = lane >> 4, l15 = lane & 15;
    int m0 = gg * 128 + wave * 16;
    int ar0 = m0 + l15;       if (ar0 > N - 1) ar0 = N - 1;
    int ar1 = m0 + 64 + l15;  if (ar1 > N - 1) ar1 = N - 1;
    const short* cp0 = ctx + (size_t)ar0 * D + quad * 8;
    const short* ap0 = atom_bf + (size_t)ar0 * D + quad * 8;
    const short* cp1 = ctx + (size_t)ar1 * D + quad * 8;
    const short* ap1 = atom_bf + (size_t)ar1 * D + quad * 8;
    const short* lb = &Bs[lane * 8];
    f32x4 gi[2][3], gh_[2][3];
    #pragma unroll
    for (int t = 0; t < 2; t++)
        #pragma unroll
        for (int j = 0; j < 3; j++) { gi[t][j] = (f32x4){0,0,0,0}; gh_[t][j] = (f32x4){0,0,0,0}; }
    #pragma unroll
    for (int kk = 0; kk < 8; kk++) {
        int k = kk * 32;
        bf16x8 c0v = *(const bf16x8*)(cp0 + k);
        bf16x8 a0v = *(const bf16x8*)(ap0 + k);
        bf16x8 c1v = *(const bf16x8*)(cp1 + k);
        bf16x8 a1v = *(const bf16x8*)(ap1 + k);
        bf16x8 bir = *(const bf16x8*)(lb + (0 * 8 + kk) * 512);
        bf16x8 biz = *(const bf16x8*)(lb + (1 * 8 + kk) * 512);
        bf16x8 bin = *(const bf16x8*)(lb + (2 * 8 + kk) * 512);
        bf16x8 bhr = *(const bf16x8*)(lb + (3 * 8 + kk) * 512);
        bf16x8 bhz = *(const bf16x8*)(lb + (4 * 8 + kk) * 512);
        bf16x8 bhn = *(const bf16x8*)(lb + (5 * 8 + kk) * 512);
        gi[0][0] = MFMA(c0v, bir, gi[0][0], 0, 0, 0);
        gi[0][1] = MFMA(c0v, biz, gi[0][1], 0, 0, 0);
        gi[0][2] = MFMA(c0v, bin, gi[0][2], 0, 0, 0);
        gh_[0][0] = MFMA(a0v, bhr, gh_[0][0], 0, 0, 0);
        gh_[0][1] = MFMA(a0v, bhz, gh_[0][1], 0, 0, 0);
        gh_[0][2] = MFMA(a0v, bhn, gh_[0][2], 0, 0, 0);
        gi[1][0] = MFMA(c1v, bir, gi[1][0], 0, 0, 0);
        gi[1][1] = MFMA(c1v, biz, gi[1][1], 0, 0, 0);
        gi[1][2] = MFMA(c1v, bin, gi[1][2], 0, 0, 0);
        gh_[1][0] = MFMA(a1v, bhr, gh_[1][0], 0, 0, 0);
        gh_[1][1] = MFMA(a1v, bhz, gh_[1][1], 0, 0, 0);
        gh_[1][2] = MFMA(a1v, bhn, gh_[1][2], 0, 0, 0);
    }
    int col = c0 + l15;
    float bir_s = b_ih[col], biz_s = b_ih[col + 256], bin_s = b_ih[col + 512];
    float bhr_s = b_hh[col], bhz_s = b_hh[col + 256], bhn_s = b_hh[col + 512];
    #pragma unroll
    for (int t = 0; t < 2; t++) {
        #pragma unroll
        for (int r = 0; r < 4; r++) {
            int row = m0 + t * 64 + quad * 4 + r;
            if (row < N) {
                float rr = 1.f / (1.f + __expf(-(gi[t][0][r] + bir_s + gh_[t][0][r] + bhr_s)));
                float zz = 1.f / (1.f + __expf(-(gi[t][1][r] + biz_s + gh_[t][1][r] + bhz_s)));
                float nn = tanhf(gi[t][2][r] + bin_s + rr * (gh_[t][2][r] + bhn_s));
                float at = s2f(atom_bf[(size_t)row * D + col]);
                out[(size_t)row * D + col] = (1.f - zz) * nn + zz * at;
            }
        }
    }
}

extern "C" void kernel_launch(void* const* d_in, const int* in_sizes, int n_in,
                              void* d_out, int out_size, void* d_ws, size_t ws_size,
                              hipStream_t stream) {
    const float* atom    = (const float*)d_in[0];
    const int*   bond    = (const int*)d_in[1];
    const float* W_align = (const float*)d_in[2];
    const float* b_align = (const float*)d_in[3];
    const float* bn_a_g  = (const float*)d_in[4];
    const float* bn_a_b  = (const float*)d_in[5];
    const float* bn_a_m  = (const float*)d_in[6];
    const float* bn_a_v  = (const float*)d_in[7];
    const float* W_att   = (const float*)d_in[8];
    const float* b_att   = (const float*)d_in[9];
    const float* bn_t_g  = (const float*)d_in[10];
    const float* bn_t_b  = (const float*)d_in[11];
    const float* bn_t_m  = (const float*)d_in[12];
    const float* bn_t_v  = (const float*)d_in[13];
    const float* W_ih    = (const float*)d_in[14];
    const float* W_hh    = (const float*)d_in[15];
    const float* b_ih    = (const float*)d_in[16];
    const float* b_hh    = (const float*)d_in[17];

    int N = in_sizes[0] / D;
    int E = in_sizes[1] / 2;
    const int* src = bond;
    const int* dst = bond + E;

    char* w = (char*)d_ws;
    size_t o = 0;
    auto alloc = [&](size_t bytes) {
        void* p = w + o;
        o = (o + bytes + 255) & ~(size_t)255;
        return p;
    };
    int*   cnt     = (int*)alloc((size_t)N * 4);
    int*   cursor  = (int*)alloc((size_t)N * 4);
    int*   offv    = (int*)alloc((size_t)(N + 1) * 4);
    int*   dlist   = (int*)alloc((size_t)E * 4);
    float* p0p     = (float*)alloc((size_t)N * 4);
    float* p1p     = (float*)alloc((size_t)N * 4);
    short* hA      = (short*)alloc((size_t)N * D * 2);
    short* ctx     = (short*)alloc((size_t)N * D * 2);
    short* atom_bf = (short*)alloc((size_t)N * D * 2);
    short* Watt_bf = (short*)alloc((size_t)D * D * 2);
    short* Wih_bf  = (short*)alloc((size_t)3 * D * D * 2);
    short* Whh_bf  = (short*)alloc((size_t)3 * D * D * 2);

    int NROWB = (N + 3) / 4;
    int nWtot4 = (D * D + 2 * 3 * D * D) / 4;
    int WCVTB = (nWtot4 + 255) / 256;
    int INITB = (N + 255) / 256;
    int TOTB = NROWB + WCVTB + INITB;

    void* args[] = {
        (void*)&atom, (void*)&atom_bf, (void*)&W_align, (void*)&b_align,
        (void*)&bn_a_g, (void*)&bn_a_b, (void*)&bn_a_m, (void*)&bn_a_v,
        (void*)&p0p, (void*)&p1p,
        (void*)&W_att, (void*)&Watt_bf, (void*)&W_ih, (void*)&Wih_bf,
        (void*)&W_hh, (void*)&Whh_bf,
        (void*)&cnt, (void*)&cursor, (void*)&offv, (void*)&dlist,
        (void*)&src, (void*)&dst,
        (void*)&N, (void*)&E, (void*)&NROWB, (void*)&WCVTB, (void*)&TOTB
    };
    hipLaunchCooperativeKernel((void*)front_kernel, dim3(256), dim3(256), args, 0, stream);

    int NB = (N + 127) / 128;
    int GH = (NB + 7) / 8;
    hA_kernel<<<8 * 4 * GH, 256, 0, stream>>>(
        atom_bf, Watt_bf, b_att, bn_t_g, bn_t_b, bn_t_m, bn_t_v, hA, N, NB);
    agg_kernel<<<((size_t)N * 64 + 255) / 256, 256, 0, stream>>>(
        offv, dlist, p0p, p1p, hA, ctx, N);
    gru_kernel<<<8 * 16 * GH, 256, 0, stream>>>(
        ctx, atom_bf, Wih_bf, Whh_bf, b_ih, b_hh, (float*)d_out, N, NB);
}

// Round 15
// 189.681 us; speedup vs baseline: 1.6844x; 1.6844x over previous
//
#include <hip/hip_runtime.h>
#include <hip/hip_bf16.h>

#define D 256

typedef __attribute__((ext_vector_type(8))) short bf16x8;
typedef __attribute__((ext_vector_type(4))) short s16x4;
typedef __attribute__((ext_vector_type(4))) float f32x4;

#define MFMA __builtin_amdgcn_mfma_f32_16x16x32_bf16

__device__ __forceinline__ float s2f(short u) {
    union { unsigned int i; float f; } c;
    c.i = ((unsigned int)(unsigned short)u) << 16;
    return c.f;
}
__device__ __forceinline__ short f2s(float f) {
    union { float f; unsigned int u; } c; c.f = f;
    unsigned int u = c.u;
    u += 0x7fffu + ((u >> 16) & 1u);
    return (short)(u >> 16);
}

// ---------------- prep: atom cvt + p0p1 (one pass), weight cvt, CSR zero ----------------
__global__ __launch_bounds__(256) void prep_kernel(
    const float* __restrict__ atom, short* __restrict__ atom_bf,
    const float* __restrict__ W_align, const float* __restrict__ b_align,
    const float* __restrict__ g, const float* __restrict__ bb,
    const float* __restrict__ mn, const float* __restrict__ vr,
    float* __restrict__ p0p, float* __restrict__ p1p,
    const float* __restrict__ Wa, short* __restrict__ Wa_bf,
    const float* __restrict__ Wi, short* __restrict__ Wi_bf,
    const float* __restrict__ Wh, short* __restrict__ Wh_bf,
    int* __restrict__ cnt, int* __restrict__ cursor,
    int N, int NROWB, int WCVTB)
{
    int b = blockIdx.x, tid = threadIdx.x;
    if (b < NROWB) {
        int wave = tid >> 6, lane = tid & 63;
        int row = b * 4 + wave;
        if (row >= N) return;
        float4 a = *(const float4*)(atom + (size_t)row * D + lane * 4);
        s16x4 o; o[0] = f2s(a.x); o[1] = f2s(a.y); o[2] = f2s(a.z); o[3] = f2s(a.w);
        ((s16x4*)(atom_bf + (size_t)row * D))[lane] = o;
        float4 w0 = *(const float4*)(W_align + lane * 4);
        float4 w1 = *(const float4*)(W_align + D + lane * 4);
        float d0 = a.x * w0.x + a.y * w0.y + a.z * w0.z + a.w * w0.w;
        float d1 = a.x * w1.x + a.y * w1.y + a.z * w1.z + a.w * w1.w;
        #pragma unroll
        for (int s = 32; s > 0; s >>= 1) {
            d0 += __shfl_xor(d0, s, 64);
            d1 += __shfl_xor(d1, s, 64);
        }
        if (lane == 0) {
            float A = rsqrtf(vr[0] + 1e-6f) * g[0];
            p0p[row] = A * (d0 + b_align[0]) + bb[0] - A * mn[0];
            p1p[row] = A * d1;
        }
        return;
    }
    b -= NROWB;
    if (b < WCVTB) {
        int nW4 = D * D / 4, nG4 = 3 * D * D / 4;
        int j = b * 256 + tid;
        const float* src; short* dst;
        if (j < nW4) { src = Wa; dst = Wa_bf; }
        else { j -= nW4;
            if (j < nG4) { src = Wi; dst = Wi_bf; }
            else { j -= nG4;
                if (j < nG4) { src = Wh; dst = Wh_bf; }
                else return;
            }
        }
        float4 v = ((const float4*)src)[j];
        s16x4 o; o[0] = f2s(v.x); o[1] = f2s(v.y); o[2] = f2s(v.z); o[3] = f2s(v.w);
        ((s16x4*)dst)[j] = o;
        return;
    }
    b -= WCVTB;
    int i = b * 256 + tid;
    if (i < N) { cnt[i] = 0; cursor[i] = 0; }
}

// ---------------- histogram of src ----------------
__global__ __launch_bounds__(256) void count_kernel(const int* __restrict__ src, int* cnt, int E) {
    int e = blockIdx.x * 256 + threadIdx.x;
    if (e < E) atomicAdd(&cnt[src[e]], 1);
}

// ---------------- exclusive scan, serial-chunk + 1024-scan (single block) ----------------
__global__ __launch_bounds__(1024) void scan_kernel(const int* __restrict__ cnt, int* __restrict__ off, int N) {
    __shared__ int sums[1024];
    int t = threadIdx.x;
    int CH = (N + 1023) / 1024;
    int beg = t * CH;
    int end = beg + CH; if (end > N) end = N;
    int s = 0;
    for (int i = beg; i < end; i++) s += cnt[i];
    sums[t] = s;
    __syncthreads();
    for (int d = 1; d < 1024; d <<= 1) {
        int x = (t >= d) ? sums[t - d] : 0;
        __syncthreads();
        sums[t] += x;
        __syncthreads();
    }
    int run = (t > 0) ? sums[t - 1] : 0;
    for (int i = beg; i < end; i++) { off[i] = run; run += cnt[i]; }
    if (end == N) off[N] = run;
}

// ---------------- fill dst-valued edge lists ----------------
__global__ __launch_bounds__(256) void fill_kernel(const int* __restrict__ src, const int* __restrict__ dst,
                                                   const int* __restrict__ off, int* cursor, int* dlist, int E) {
    int e = blockIdx.x * 256 + threadIdx.x;
    if (e < E) {
        int s = src[e];
        int p = atomicAdd(&cursor[s], 1);
        dlist[off[s] + p] = dst[e];
    }
}

// ---------------- hA = BN(atom @ W_att^T + b_att), MFMA + lane-ordered LDS B ----------------
__global__ __launch_bounds__(256) void hA_kernel(
    const short* __restrict__ atom_bf, const short* __restrict__ W_bf,
    const float* __restrict__ bias,
    const float* __restrict__ g, const float* __restrict__ bb,
    const float* __restrict__ mn, const float* __restrict__ vr,
    short* __restrict__ hA, int N, int NB)
{
    __shared__ short Bs[2048 * 8];       // 32KB, lane-ordered chunks
    int bi = blockIdx.x;
    int xcd = bi & 7, rest = bi >> 3;
    int cb = rest & 3, gh = rest >> 2;
    int gg = gh * 8 + xcd;
    if (gg >= NB) return;
    int c0 = cb * 64;
    int tid = threadIdx.x;
    for (int c = tid; c < 2048; c += 256) {
        int l15c = c & 15, quadc = (c >> 4) & 3, t2 = c >> 6;
        int kkc = t2 & 7, jc = t2 >> 3;
        bf16x8 v = *(const bf16x8*)(W_bf + (size_t)(c0 + jc * 16 + l15c) * D + quadc * 8 + kkc * 32);
        *(bf16x8*)(&Bs[c * 8]) = v;
    }
    __syncthreads();

    int wave = tid >> 6, lane = tid & 63;
    int quad = lane >> 4, l15 = lane & 15;
    int m0 = gg * 128 + wave * 16;
    int ar0 = m0 + l15;       if (ar0 > N - 1) ar0 = N - 1;
    int ar1 = m0 + 64 + l15;  if (ar1 > N - 1) ar1 = N - 1;
    const short* ap0 = atom_bf + (size_t)ar0 * D + quad * 8;
    const short* ap1 = atom_bf + (size_t)ar1 * D + quad * 8;
    const short* lb = &Bs[lane * 8];
    f32x4 acc[2][4];
    #pragma unroll
    for (int t = 0; t < 2; t++)
        #pragma unroll
        for (int j = 0; j < 4; j++) acc[t][j] = (f32x4){0,0,0,0};
    #pragma unroll
    for (int kk = 0; kk < 8; kk++) {
        int k = kk * 32;
        bf16x8 a0 = *(const bf16x8*)(ap0 + k);
        bf16x8 a1 = *(const bf16x8*)(ap1 + k);
        bf16x8 b0 = *(const bf16x8*)(lb + (0 * 8 + kk) * 512);
        bf16x8 b1 = *(const bf16x8*)(lb + (1 * 8 + kk) * 512);
        bf16x8 b2 = *(const bf16x8*)(lb + (2 * 8 + kk) * 512);
        bf16x8 b3 = *(const bf16x8*)(lb + (3 * 8 + kk) * 512);
        acc[0][0] = MFMA(a0, b0, acc[0][0], 0, 0, 0);
        acc[0][1] = MFMA(a0, b1, acc[0][1], 0, 0, 0);
        acc[0][2] = MFMA(a0, b2, acc[0][2], 0, 0, 0);
        acc[0][3] = MFMA(a0, b3, acc[0][3], 0, 0, 0);
        acc[1][0] = MFMA(a1, b0, acc[1][0], 0, 0, 0);
        acc[1][1] = MFMA(a1, b1, acc[1][1], 0, 0, 0);
        acc[1][2] = MFMA(a1, b2, acc[1][2], 0, 0, 0);
        acc[1][3] = MFMA(a1, b3, acc[1][3], 0, 0, 0);
    }
    #pragma unroll
    for (int j = 0; j < 4; j++) {
        int col = c0 + j * 16 + l15;
        float sc = rsqrtf(vr[col] + 1e-6f) * g[col];
        float sh = bb[col] - mn[col] * sc;
        float bi_ = bias[col];
        #pragma unroll
        for (int t = 0; t < 2; t++) {
            #pragma unroll
            for (int r = 0; r < 4; r++) {
                int row = m0 + t * 64 + quad * 4 + r;
                if (row < N) hA[(size_t)row * D + col] = f2s((acc[t][j][r] + bi_) * sc + sh);
            }
        }
    }
}

// ---------------- fused score+softmax+aggregate, SINGLE CSR pass (wave per atom) ----------------
// attn_j = exp(x_j)/(sum exp + 1e-8) computed by deferred normalization:
// acc = sum e_j * h[d_j]; se = sum e_j; ctx = ELU(acc/(se+1e-8)). Scores |x|<~8 so raw exp is safe.
__global__ __launch_bounds__(256) void agg_kernel(
    const int* __restrict__ off, const int* __restrict__ dlist,
    const float* __restrict__ p0p, const float* __restrict__ p1p,
    const short* __restrict__ hA, short* __restrict__ ctx, int N)
{
    int w = (blockIdx.x * blockDim.x + threadIdx.x) >> 6;
    int lane = threadIdx.x & 63;
    if (w >= N) return;
    int beg = off[w], end = off[w + 1];
    float u = p0p[w];
    int half = lane >> 5, l32 = lane & 31;
    float acc[8] = {0.f,0.f,0.f,0.f,0.f,0.f,0.f,0.f};
    float se = 0.f;
    for (int j = beg + half; j < end; j += 2) {
        int d = dlist[j];
        float x = u + p1p[d];
        x = x > 0.f ? x : 0.01f * x;
        float e = __expf(x);
        se += e;
        bf16x8 h = *(const bf16x8*)(hA + (size_t)d * D + l32 * 8);
        #pragma unroll
        for (int i = 0; i < 8; i++) acc[i] += e * s2f(h[i]);
    }
    se += __shfl_xor(se, 32, 64);
    #pragma unroll
    for (int i = 0; i < 8; i++) acc[i] += __shfl_xor(acc[i], 32, 64);
    if (half == 0) {
        float inv = 1.f / (se + 1e-8f);
        bf16x8 o;
        #pragma unroll
        for (int i = 0; i < 8; i++) {
            float v = acc[i] * inv;
            v = v > 0.f ? v : __expf(v) - 1.f;
            o[i] = f2s(v);
        }
        *(bf16x8*)(ctx + (size_t)w * D + l32 * 8) = o;
    }
}

// ---------------- fused GRU cell, MFMA + lane-ordered LDS B; OUTPUT FLOAT32 ----------------
__global__ __launch_bounds__(256) void gru_kernel(
    const short* __restrict__ ctx, const short* __restrict__ atom_bf,
    const short* __restrict__ W_ih, const short* __restrict__ W_hh,
    const float* __restrict__ b_ih, const float* __restrict__ b_hh,
    float* __restrict__ out, int N, int NB)
{
    __shared__ short Bs[3072 * 8];   // 48KB, lane-ordered chunks
    int bi = blockIdx.x;
    int xcd = bi & 7, rest = bi >> 3;
    int cb = rest & 15, gh = rest >> 4;
    int gg = gh * 8 + xcd;
    if (gg >= NB) return;
    int c0 = cb * 16;
    int tid = threadIdx.x;
    for (int c = tid; c < 3072; c += 256) {
        int l15c = c & 15, quadc = (c >> 4) & 3, t2 = c >> 6;
        int kkc = t2 & 7, gate = t2 >> 3;
        const short* srcp = (gate < 3)
            ? W_ih + (size_t)(gate * 256 + c0 + l15c) * D + quadc * 8 + kkc * 32
            : W_hh + (size_t)((gate - 3) * 256 + c0 + l15c) * D + quadc * 8 + kkc * 32;
        *(bf16x8*)(&Bs[c * 8]) = *(const bf16x8*)srcp;
    }
    __syncthreads();

    int wave = tid >> 6, lane = tid & 63;
    int quad = lane >> 4, l15 = lane & 15;
    int m0 = gg * 128 + wave * 16;
    int ar0 = m0 + l15;       if (ar0 > N - 1) ar0 = N - 1;
    int ar1 = m0 + 64 + l15;  if (ar1 > N - 1) ar1 = N - 1;
    const short* cp0 = ctx + (size_t)ar0 * D + quad * 8;
    const short* ap0 = atom_bf + (size_t)ar0 * D + quad * 8;
    const short* cp1 = ctx + (size_t)ar1 * D + quad * 8;
    const short* ap1 = atom_bf + (size_t)ar1 * D + quad * 8;
    const short* lb = &Bs[lane * 8];
    f32x4 gi[2][3], gh_[2][3];
    #pragma unroll
    for (int t = 0; t < 2; t++)
        #pragma unroll
        for (int j = 0; j < 3; j++) { gi[t][j] = (f32x4){0,0,0,0}; gh_[t][j] = (f32x4){0,0,0,0}; }
    #pragma unroll
    for (int kk = 0; kk < 8; kk++) {
        int k = kk * 32;
        bf16x8 c0v = *(const bf16x8*)(cp0 + k);
        bf16x8 a0v = *(const bf16x8*)(ap0 + k);
        bf16x8 c1v = *(const bf16x8*)(cp1 + k);
        bf16x8 a1v = *(const bf16x8*)(ap1 + k);
        bf16x8 bir = *(const bf16x8*)(lb + (0 * 8 + kk) * 512);
        bf16x8 biz = *(const bf16x8*)(lb + (1 * 8 + kk) * 512);
        bf16x8 bin = *(const bf16x8*)(lb + (2 * 8 + kk) * 512);
        bf16x8 bhr = *(const bf16x8*)(lb + (3 * 8 + kk) * 512);
        bf16x8 bhz = *(const bf16x8*)(lb + (4 * 8 + kk) * 512);
        bf16x8 bhn = *(const bf16x8*)(lb + (5 * 8 + kk) * 512);
        gi[0][0] = MFMA(c0v, bir, gi[0][0], 0, 0, 0);
        gi[0][1] = MFMA(c0v, biz, gi[0][1], 0, 0, 0);
        gi[0][2] = MFMA(c0v, bin, gi[0][2], 0, 0, 0);
        gh_[0][0] = MFMA(a0v, bhr, gh_[0][0], 0, 0, 0);
        gh_[0][1] = MFMA(a0v, bhz, gh_[0][1], 0, 0, 0);
        gh_[0][2] = MFMA(a0v, bhn, gh_[0][2], 0, 0, 0);
        gi[1][0] = MFMA(c1v, bir, gi[1][0], 0, 0, 0);
        gi[1][1] = MFMA(c1v, biz, gi[1][1], 0, 0, 0);
        gi[1][2] = MFMA(c1v, bin, gi[1][2], 0, 0, 0);
        gh_[1][0] = MFMA(a1v, bhr, gh_[1][0], 0, 0, 0);
        gh_[1][1] = MFMA(a1v, bhz, gh_[1][1], 0, 0, 0);
        gh_[1][2] = MFMA(a1v, bhn, gh_[1][2], 0, 0, 0);
    }
    int col = c0 + l15;
    float bir_s = b_ih[col], biz_s = b_ih[col + 256], bin_s = b_ih[col + 512];
    float bhr_s = b_hh[col], bhz_s = b_hh[col + 256], bhn_s = b_hh[col + 512];
    #pragma unroll
    for (int t = 0; t < 2; t++) {
        #pragma unroll
        for (int r = 0; r < 4; r++) {
            int row = m0 + t * 64 + quad * 4 + r;
            if (row < N) {
                float rr = 1.f / (1.f + __expf(-(gi[t][0][r] + bir_s + gh_[t][0][r] + bhr_s)));
                float zz = 1.f / (1.f + __expf(-(gi[t][1][r] + biz_s + gh_[t][1][r] + bhz_s)));
                float nn = tanhf(gi[t][2][r] + bin_s + rr * (gh_[t][2][r] + bhn_s));
                float at = s2f(atom_bf[(size_t)row * D + col]);
                out[(size_t)row * D + col] = (1.f - zz) * nn + zz * at;
            }
        }
    }
}

extern "C" void kernel_launch(void* const* d_in, const int* in_sizes, int n_in,
                              void* d_out, int out_size, void* d_ws, size_t ws_size,
                              hipStream_t stream) {
    const float* atom    = (const float*)d_in[0];
    const int*   bond    = (const int*)d_in[1];
    const float* W_align = (const float*)d_in[2];
    const float* b_align = (const float*)d_in[3];
    const float* bn_a_g  = (const float*)d_in[4];
    const float* bn_a_b  = (const float*)d_in[5];
    const float* bn_a_m  = (const float*)d_in[6];
    const float* bn_a_v  = (const float*)d_in[7];
    const float* W_att   = (const float*)d_in[8];
    const float* b_att   = (const float*)d_in[9];
    const float* bn_t_g  = (const float*)d_in[10];
    const float* bn_t_b  = (const float*)d_in[11];
    const float* bn_t_m  = (const float*)d_in[12];
    const float* bn_t_v  = (const float*)d_in[13];
    const float* W_ih    = (const float*)d_in[14];
    const float* W_hh    = (const float*)d_in[15];
    const float* b_ih    = (const float*)d_in[16];
    const float* b_hh    = (const float*)d_in[17];

    int N = in_sizes[0] / D;
    int E = in_sizes[1] / 2;
    const int* src = bond;
    const int* dst = bond + E;

    char* w = (char*)d_ws;
    size_t o = 0;
    auto alloc = [&](size_t bytes) {
        void* p = w + o;
        o = (o + bytes + 255) & ~(size_t)255;
        return p;
    };
    int*   cnt     = (int*)alloc((size_t)N * 4);
    int*   cursor  = (int*)alloc((size_t)N * 4);
    int*   offv    = (int*)alloc((size_t)(N + 1) * 4);
    int*   dlist   = (int*)alloc((size_t)E * 4);
    float* p0p     = (float*)alloc((size_t)N * 4);
    float* p1p     = (float*)alloc((size_t)N * 4);
    short* hA      = (short*)alloc((size_t)N * D * 2);
    short* ctx     = (short*)alloc((size_t)N * D * 2);
    short* atom_bf = (short*)alloc((size_t)N * D * 2);
    short* Watt_bf = (short*)alloc((size_t)D * D * 2);
    short* Wih_bf  = (short*)alloc((size_t)3 * D * D * 2);
    short* Whh_bf  = (short*)alloc((size_t)3 * D * D * 2);

    int NROWB = (N + 3) / 4;
    int nWtot4 = (D * D + 2 * 3 * D * D) / 4;
    int WCVTB = (nWtot4 + 255) / 256;
    int INITB = (N + 255) / 256;
    prep_kernel<<<NROWB + WCVTB + INITB, 256, 0, stream>>>(
        atom, atom_bf, W_align, b_align, bn_a_g, bn_a_b, bn_a_m, bn_a_v, p0p, p1p,
        W_att, Watt_bf, W_ih, Wih_bf, W_hh, Whh_bf, cnt, cursor, N, NROWB, WCVTB);
    count_kernel<<<(E + 255) / 256, 256, 0, stream>>>(src, cnt, E);
    scan_kernel<<<1, 1024, 0, stream>>>(cnt, offv, N);
    fill_kernel<<<(E + 255) / 256, 256, 0, stream>>>(src, dst, offv, cursor, dlist, E);

    int NB = (N + 127) / 128;
    int GH = (NB + 7) / 8;
    hA_kernel<<<8 * 4 * GH, 256, 0, stream>>>(
        atom_bf, Watt_bf, b_att, bn_t_g, bn_t_b, bn_t_m, bn_t_v, hA, N, NB);
    agg_kernel<<<((size_t)N * 64 + 255) / 256, 256, 0, stream>>>(
        offv, dlist, p0p, p1p, hA, ctx, N);
    gru_kernel<<<8 * 16 * GH, 256, 0, stream>>>(
        ctx, atom_bf, Wih_bf, Whh_bf, b_ih, b_hh, (float*)d_out, N, NB);
}